// Round 3
// baseline (116.878 us; speedup 1.0000x reference)
//
#include <hip/hip_runtime.h>
#include <hip/hip_bf16.h>
#include <math.h>

#define SS 2048
#define HH 16
#define DD 128
#define HD (HH*DD)
#define QBLK 64
#define KVBLK 64
#define CH 8                     // KV tiles per chunk (split-KV granularity)
#define NTASK_PER_H 80           // sum over qt of ceil((qt+1)/CH)
#define NTASK (NTASK_PER_H*HH)   // 1280

typedef __attribute__((ext_vector_type(8))) short bf16x8;
typedef __attribute__((ext_vector_type(4))) float f32x4;

#define EXP2(x) exp2f(x)

__device__ __forceinline__ ushort f2bf(float f) {
  __hip_bfloat16 h = __float2bfloat16(f);
  return __builtin_bit_cast(ushort, h);
}

// ---------------------------------------------------------------------------
// Kernel 1: per-chunk partial attention. Task = (h, qt, chunk c).
// Writes unnormalized acc + per-row (m, l) to workspace.
// ---------------------------------------------------------------------------
__global__ __launch_bounds__(256, 3)
void attn_partial(const float* __restrict__ Q, const float* __restrict__ K,
                  const float* __restrict__ V, float* __restrict__ PO,
                  float* __restrict__ PM, float* __restrict__ PL) {
  __shared__ alignas(16) ushort Klds[KVBLK][136];
  __shared__ alignas(16) ushort VTlds[DD][72];
  __shared__ alignas(16) ushort Plds[4][16][72];

  const int tid  = threadIdx.x;
  const int lane = tid & 63;
  const int wid  = tid >> 6;
  const int n    = lane & 15;
  const int g    = lane >> 4;

  const int bx   = blockIdx.x;        // 0..NTASK-1
  const int h    = bx & 15;
  const int task = bx >> 4;           // 0..79

  // decode task -> (qt, c): base(qt) = qt + 4a(a-1) + a*b, a=qt>>3, b=qt&7
  int qt = 0, c = 0;
  for (int q = 31; q >= 0; --q) {
    int a = q >> 3, b = q & 7;
    int base = q + 4 * a * (a - 1) + a * b;
    if (task >= base) { qt = q; c = task - base; break; }
  }

  const int qb = qt * QBLK;
  const int qw = qb + 16 * wid;
  const int nt = qb / KVBLK + 1;            // total KV tiles for this q-tile
  const int tile_lo = c * CH;
  const int tile_hi = min(tile_lo + CH, nt);

  const float SCALE = 1.44269504088896f / sqrtf((float)DD);

  // ---- preload Q fragments, scaled, bf16 ----
  bf16x8 qfrag[4];
  {
    const float* qrow = Q + ((size_t)(qw + n) * HH + h) * DD;
    #pragma unroll
    for (int ks = 0; ks < 4; ++ks) {
      const int d0 = 32 * ks + 8 * g;
      float4 x = *(const float4*)&qrow[d0];
      float4 y = *(const float4*)&qrow[d0 + 4];
      bf16x8 a;
      a[0] = (short)f2bf(x.x * SCALE); a[1] = (short)f2bf(x.y * SCALE);
      a[2] = (short)f2bf(x.z * SCALE); a[3] = (short)f2bf(x.w * SCALE);
      a[4] = (short)f2bf(y.x * SCALE); a[5] = (short)f2bf(y.y * SCALE);
      a[6] = (short)f2bf(y.z * SCALE); a[7] = (short)f2bf(y.w * SCALE);
      qfrag[ks] = a;
    }
  }

  f32x4 acc[8];
  #pragma unroll
  for (int d0 = 0; d0 < 8; ++d0) { acc[d0][0]=0.f; acc[d0][1]=0.f; acc[d0][2]=0.f; acc[d0][3]=0.f; }
  float m[4] = { -INFINITY, -INFINITY, -INFINITY, -INFINITY };
  float l[4] = { 0.f, 0.f, 0.f, 0.f };

  const float* Kbase = K + (size_t)h * DD;
  const float* Vbase = V + (size_t)h * DD;

  float4 kreg[8];
  float4 vreg[8];

  // prefetch first tile of this chunk
  {
    const int t0 = tile_lo * KVBLK;
    #pragma unroll
    for (int it = 0; it < 8; ++it) {
      int li = tid + it * 256;
      int t  = li >> 5;
      int c4 = (li & 31) << 2;
      kreg[it] = *(const float4*)&Kbase[(size_t)(t0 + t) * HD + c4];
    }
    const int dd0 = wid * 16 + n;
    #pragma unroll
    for (int half = 0; half < 2; ++half) {
      #pragma unroll
      for (int jj = 0; jj < 4; ++jj) {
        const float* vp = &Vbase[(size_t)(t0 + 16 * jj + 4 * g) * HD + (dd0 + 64 * half)];
        vreg[half * 4 + jj] = make_float4(vp[0], vp[HD], vp[2 * HD], vp[3 * HD]);
      }
    }
  }

  for (int itile = tile_lo; itile < tile_hi; ++itile) {
    __syncthreads();

    // ---- regs -> LDS (bf16) ----
    #pragma unroll
    for (int it = 0; it < 8; ++it) {
      int li = tid + it * 256;
      int t  = li >> 5;
      int c4 = (li & 31) << 2;
      float4 x = kreg[it];
      ushort4 w;
      w.x = f2bf(x.x); w.y = f2bf(x.y); w.z = f2bf(x.z); w.w = f2bf(x.w);
      *(ushort4*)&Klds[t][c4] = w;
    }
    {
      const int dd0 = wid * 16 + n;
      #pragma unroll
      for (int half = 0; half < 2; ++half) {
        #pragma unroll
        for (int jj = 0; jj < 4; ++jj) {
          float4 x = vreg[half * 4 + jj];
          ushort4 w;
          w.x = f2bf(x.x); w.y = f2bf(x.y); w.z = f2bf(x.z); w.w = f2bf(x.w);
          *(ushort4*)&VTlds[dd0 + 64 * half][16 * jj + 4 * g] = w;
        }
      }
    }
    __syncthreads();

    // ---- prefetch next tile ----
    if (itile + 1 < tile_hi) {
      const int t0n = (itile + 1) * KVBLK;
      #pragma unroll
      for (int it = 0; it < 8; ++it) {
        int li = tid + it * 256;
        int t  = li >> 5;
        int c4 = (li & 31) << 2;
        kreg[it] = *(const float4*)&Kbase[(size_t)(t0n + t) * HD + c4];
      }
      const int dd0 = wid * 16 + n;
      #pragma unroll
      for (int half = 0; half < 2; ++half) {
        #pragma unroll
        for (int jj = 0; jj < 4; ++jj) {
          const float* vp = &Vbase[(size_t)(t0n + 16 * jj + 4 * g) * HD + (dd0 + 64 * half)];
          vreg[half * 4 + jj] = make_float4(vp[0], vp[HD], vp[2 * HD], vp[3 * HD]);
        }
      }
    }

    const int t0 = itile * KVBLK;

    // ---- QK^T ----
    f32x4 s[4];
    #pragma unroll
    for (int sub = 0; sub < 4; ++sub) { s[sub][0]=0.f; s[sub][1]=0.f; s[sub][2]=0.f; s[sub][3]=0.f; }
    #pragma unroll
    for (int ks = 0; ks < 4; ++ks) {
      #pragma unroll
      for (int sub = 0; sub < 4; ++sub) {
        bf16x8 b = *(const bf16x8*)&Klds[sub * 16 + n][32 * ks + 8 * g];
        s[sub] = __builtin_amdgcn_mfma_f32_16x16x32_bf16(qfrag[ks], b, s[sub], 0, 0, 0);
      }
    }

    // ---- causal mask (diagonal tiles only) ----
    if (t0 + KVBLK - 1 > qw) {
      #pragma unroll
      for (int sub = 0; sub < 4; ++sub) {
        int tg = t0 + sub * 16 + n;
        #pragma unroll
        for (int r = 0; r < 4; ++r) {
          int qg = qw + 4 * g + r;
          if (tg > qg) s[sub][r] = -INFINITY;
        }
      }
    }

    // ---- online softmax (log2 domain) ----
    float mr[4];
    #pragma unroll
    for (int r = 0; r < 4; ++r)
      mr[r] = fmaxf(fmaxf(s[0][r], s[1][r]), fmaxf(s[2][r], s[3][r]));
    #pragma unroll
    for (int off = 1; off <= 8; off <<= 1) {
      #pragma unroll
      for (int r = 0; r < 4; ++r)
        mr[r] = fmaxf(mr[r], __shfl_xor(mr[r], off));
    }
    float corr[4];
    #pragma unroll
    for (int r = 0; r < 4; ++r) {
      float mn = fmaxf(m[r], mr[r]);
      corr[r] = EXP2(m[r] - mn);
      m[r] = mn;
    }
    float sr[4] = { 0.f, 0.f, 0.f, 0.f };
    #pragma unroll
    for (int sub = 0; sub < 4; ++sub) {
      #pragma unroll
      for (int r = 0; r < 4; ++r) {
        float p = EXP2(s[sub][r] - m[r]);
        sr[r] += p;
        Plds[wid][4 * g + r][sub * 16 + n] = f2bf(p);
      }
    }
    #pragma unroll
    for (int off = 1; off <= 8; off <<= 1) {
      #pragma unroll
      for (int r = 0; r < 4; ++r)
        sr[r] += __shfl_xor(sr[r], off);
    }
    #pragma unroll
    for (int r = 0; r < 4; ++r) l[r] = l[r] * corr[r] + sr[r];
    #pragma unroll
    for (int d0 = 0; d0 < 8; ++d0) {
      #pragma unroll
      for (int r = 0; r < 4; ++r) acc[d0][r] *= corr[r];
    }

    // ---- PV ----
    #pragma unroll
    for (int ks = 0; ks < 2; ++ks) {
      bf16x8 a = *(const bf16x8*)&Plds[wid][n][32 * ks + 8 * g];
      #pragma unroll
      for (int d0 = 0; d0 < 8; ++d0) {
        bf16x8 b = *(const bf16x8*)&VTlds[d0 * 16 + n][32 * ks + 8 * g];
        acc[d0] = __builtin_amdgcn_mfma_f32_16x16x32_bf16(a, b, acc[d0], 0, 0, 0);
      }
    }
  }

  // ---- write partials (unnormalized) ----
  float* po = PO + (size_t)bx * (QBLK * DD);
  #pragma unroll
  for (int d0 = 0; d0 < 8; ++d0) {
    #pragma unroll
    for (int r = 0; r < 4; ++r) {
      po[(16 * wid + 4 * g + r) * DD + d0 * 16 + n] = acc[d0][r];
    }
  }
  if (n == 0) {
    #pragma unroll
    for (int r = 0; r < 4; ++r) {
      PM[(size_t)bx * QBLK + 16 * wid + 4 * g + r] = m[r];
      PL[(size_t)bx * QBLK + 16 * wid + 4 * g + r] = l[r];
    }
  }
}

// ---------------------------------------------------------------------------
// Kernel 2: combine partials for each (h, qt).
// ---------------------------------------------------------------------------
__global__ __launch_bounds__(256, 4)
void attn_combine(const float* __restrict__ PO, const float* __restrict__ PM,
                  const float* __restrict__ PL, float* __restrict__ O) {
  const int bx = blockIdx.x;     // 0..511
  const int h  = bx & 15;
  const int qt = bx >> 4;
  const int tid = threadIdx.x;
  const int r  = tid >> 2;            // row 0..63
  const int d0 = (tid & 3) << 5;      // 0,32,64,96

  const int a = qt >> 3, b = qt & 7;
  const int base = qt + 4 * a * (a - 1) + a * b;
  const int nc = a + 1;

  float mc[4], lc[4];
  float M = -INFINITY;
  for (int cc = 0; cc < nc; ++cc) {
    int pid = ((base + cc) << 4) | h;
    mc[cc] = PM[(size_t)pid * QBLK + r];
    lc[cc] = PL[(size_t)pid * QBLK + r];
    M = fmaxf(M, mc[cc]);
  }
  float L = 0.f;
  float4 o[8];
  #pragma unroll
  for (int k = 0; k < 8; ++k) o[k] = make_float4(0.f, 0.f, 0.f, 0.f);
  for (int cc = 0; cc < nc; ++cc) {
    int pid = ((base + cc) << 4) | h;
    float w = EXP2(mc[cc] - M);
    L += lc[cc] * w;
    const float* po = PO + (size_t)pid * (QBLK * DD) + r * DD + d0;
    #pragma unroll
    for (int k = 0; k < 8; ++k) {
      float4 x = *(const float4*)&po[4 * k];
      o[k].x += x.x * w; o[k].y += x.y * w; o[k].z += x.z * w; o[k].w += x.w * w;
    }
  }
  float inv = 1.0f / L;
  float* op = O + ((size_t)(qt * QBLK + r) * HH + h) * DD + d0;
  #pragma unroll
  for (int k = 0; k < 8; ++k) {
    float4 x = make_float4(o[k].x * inv, o[k].y * inv, o[k].z * inv, o[k].w * inv);
    *(float4*)&op[4 * k] = x;
  }
}

// ---------------------------------------------------------------------------
// Fallback: single-pass kernel (proven, 75.9 us) if ws too small.
// ---------------------------------------------------------------------------
__global__ __launch_bounds__(256, 2)
void attn_fwd(const float* __restrict__ Q, const float* __restrict__ K,
              const float* __restrict__ V, float* __restrict__ O) {
  __shared__ alignas(16) ushort Klds[KVBLK][136];
  __shared__ alignas(16) ushort VTlds[DD][72];
  __shared__ alignas(16) ushort Plds[4][16][72];

  const int tid  = threadIdx.x;
  const int lane = tid & 63;
  const int wid  = tid >> 6;
  const int n    = lane & 15;
  const int g    = lane >> 4;

  const int h  = blockIdx.x & (HH - 1);
  const int j  = blockIdx.x >> 4;
  const int qt = (j < 16) ? (31 - j) : (j - 16);
  const int qb = qt * QBLK;
  const int qw = qb + 16 * wid;

  const float SCALE = 1.44269504088896f / sqrtf((float)DD);

  bf16x8 qfrag[4];
  {
    const float* qrow = Q + ((size_t)(qw + n) * HH + h) * DD;
    #pragma unroll
    for (int ks = 0; ks < 4; ++ks) {
      const int d0 = 32 * ks + 8 * g;
      float4 x = *(const float4*)&qrow[d0];
      float4 y = *(const float4*)&qrow[d0 + 4];
      bf16x8 a;
      a[0] = (short)f2bf(x.x * SCALE); a[1] = (short)f2bf(x.y * SCALE);
      a[2] = (short)f2bf(x.z * SCALE); a[3] = (short)f2bf(x.w * SCALE);
      a[4] = (short)f2bf(y.x * SCALE); a[5] = (short)f2bf(y.y * SCALE);
      a[6] = (short)f2bf(y.z * SCALE); a[7] = (short)f2bf(y.w * SCALE);
      qfrag[ks] = a;
    }
  }

  f32x4 acc[8];
  #pragma unroll
  for (int d0 = 0; d0 < 8; ++d0) { acc[d0][0]=0.f; acc[d0][1]=0.f; acc[d0][2]=0.f; acc[d0][3]=0.f; }
  float m[4] = { -INFINITY, -INFINITY, -INFINITY, -INFINITY };
  float l[4] = { 0.f, 0.f, 0.f, 0.f };

  const float* Kbase = K + (size_t)h * DD;
  const float* Vbase = V + (size_t)h * DD;
  const int nt = qb / KVBLK + 1;

  float4 kreg[8];
  float4 vreg[8];
  {
    #pragma unroll
    for (int it = 0; it < 8; ++it) {
      int li = tid + it * 256;
      int t  = li >> 5;
      int c4 = (li & 31) << 2;
      kreg[it] = *(const float4*)&Kbase[(size_t)t * HD + c4];
    }
    const int dd0 = wid * 16 + n;
    #pragma unroll
    for (int half = 0; half < 2; ++half) {
      #pragma unroll
      for (int jj = 0; jj < 4; ++jj) {
        const float* vp = &Vbase[(size_t)(16 * jj + 4 * g) * HD + (dd0 + 64 * half)];
        vreg[half * 4 + jj] = make_float4(vp[0], vp[HD], vp[2 * HD], vp[3 * HD]);
      }
    }
  }

  for (int itile = 0; itile < nt; ++itile) {
    __syncthreads();
    #pragma unroll
    for (int it = 0; it < 8; ++it) {
      int li = tid + it * 256;
      int t  = li >> 5;
      int c4 = (li & 31) << 2;
      float4 x = kreg[it];
      ushort4 w;
      w.x = f2bf(x.x); w.y = f2bf(x.y); w.z = f2bf(x.z); w.w = f2bf(x.w);
      *(ushort4*)&Klds[t][c4] = w;
    }
    {
      const int dd0 = wid * 16 + n;
      #pragma unroll
      for (int half = 0; half < 2; ++half) {
        #pragma unroll
        for (int jj = 0; jj < 4; ++jj) {
          float4 x = vreg[half * 4 + jj];
          ushort4 w;
          w.x = f2bf(x.x); w.y = f2bf(x.y); w.z = f2bf(x.z); w.w = f2bf(x.w);
          *(ushort4*)&VTlds[dd0 + 64 * half][16 * jj + 4 * g] = w;
        }
      }
    }
    __syncthreads();

    if (itile + 1 < nt) {
      const int t0n = (itile + 1) * KVBLK;
      #pragma unroll
      for (int it = 0; it < 8; ++it) {
        int li = tid + it * 256;
        int t  = li >> 5;
        int c4 = (li & 31) << 2;
        kreg[it] = *(const float4*)&Kbase[(size_t)(t0n + t) * HD + c4];
      }
      const int dd0 = wid * 16 + n;
      #pragma unroll
      for (int half = 0; half < 2; ++half) {
        #pragma unroll
        for (int jj = 0; jj < 4; ++jj) {
          const float* vp = &Vbase[(size_t)(t0n + 16 * jj + 4 * g) * HD + (dd0 + 64 * half)];
          vreg[half * 4 + jj] = make_float4(vp[0], vp[HD], vp[2 * HD], vp[3 * HD]);
        }
      }
    }

    const int t0 = itile * KVBLK;
    f32x4 s[4];
    #pragma unroll
    for (int sub = 0; sub < 4; ++sub) { s[sub][0]=0.f; s[sub][1]=0.f; s[sub][2]=0.f; s[sub][3]=0.f; }
    #pragma unroll
    for (int ks = 0; ks < 4; ++ks) {
      #pragma unroll
      for (int sub = 0; sub < 4; ++sub) {
        bf16x8 b = *(const bf16x8*)&Klds[sub * 16 + n][32 * ks + 8 * g];
        s[sub] = __builtin_amdgcn_mfma_f32_16x16x32_bf16(qfrag[ks], b, s[sub], 0, 0, 0);
      }
    }
    if (t0 + KVBLK - 1 > qw) {
      #pragma unroll
      for (int sub = 0; sub < 4; ++sub) {
        int tg = t0 + sub * 16 + n;
        #pragma unroll
        for (int r = 0; r < 4; ++r) {
          int qg = qw + 4 * g + r;
          if (tg > qg) s[sub][r] = -INFINITY;
        }
      }
    }
    float mr[4];
    #pragma unroll
    for (int r = 0; r < 4; ++r)
      mr[r] = fmaxf(fmaxf(s[0][r], s[1][r]), fmaxf(s[2][r], s[3][r]));
    #pragma unroll
    for (int off = 1; off <= 8; off <<= 1) {
      #pragma unroll
      for (int r = 0; r < 4; ++r)
        mr[r] = fmaxf(mr[r], __shfl_xor(mr[r], off));
    }
    float corr[4];
    #pragma unroll
    for (int r = 0; r < 4; ++r) {
      float mn = fmaxf(m[r], mr[r]);
      corr[r] = EXP2(m[r] - mn);
      m[r] = mn;
    }
    float sr[4] = { 0.f, 0.f, 0.f, 0.f };
    #pragma unroll
    for (int sub = 0; sub < 4; ++sub) {
      #pragma unroll
      for (int r = 0; r < 4; ++r) {
        float p = EXP2(s[sub][r] - m[r]);
        sr[r] += p;
        Plds[wid][4 * g + r][sub * 16 + n] = f2bf(p);
      }
    }
    #pragma unroll
    for (int off = 1; off <= 8; off <<= 1) {
      #pragma unroll
      for (int r = 0; r < 4; ++r)
        sr[r] += __shfl_xor(sr[r], off);
    }
    #pragma unroll
    for (int r = 0; r < 4; ++r) l[r] = l[r] * corr[r] + sr[r];
    #pragma unroll
    for (int d0 = 0; d0 < 8; ++d0) {
      #pragma unroll
      for (int r = 0; r < 4; ++r) acc[d0][r] *= corr[r];
    }
    #pragma unroll
    for (int ks = 0; ks < 2; ++ks) {
      bf16x8 a = *(const bf16x8*)&Plds[wid][n][32 * ks + 8 * g];
      #pragma unroll
      for (int d0 = 0; d0 < 8; ++d0) {
        bf16x8 b = *(const bf16x8*)&VTlds[d0 * 16 + n][32 * ks + 8 * g];
        acc[d0] = __builtin_amdgcn_mfma_f32_16x16x32_bf16(a, b, acc[d0], 0, 0, 0);
      }
    }
  }

  float invl[4];
  #pragma unroll
  for (int r = 0; r < 4; ++r) invl[r] = 1.0f / l[r];
  #pragma unroll
  for (int d0 = 0; d0 < 8; ++d0) {
    #pragma unroll
    for (int r = 0; r < 4; ++r) {
      O[((size_t)(qw + 4 * g + r) * HH + h) * DD + d0 * 16 + n] = acc[d0][r] * invl[r];
    }
  }
}

extern "C" void kernel_launch(void* const* d_in, const int* in_sizes, int n_in,
                              void* d_out, int out_size, void* d_ws, size_t ws_size,
                              hipStream_t stream) {
  const float* Q = (const float*)d_in[0];
  const float* K = (const float*)d_in[1];
  const float* V = (const float*)d_in[2];
  float* O = (float*)d_out;

  const size_t po_elems = (size_t)NTASK * QBLK * DD;       // 10,485,760
  const size_t ml_elems = (size_t)NTASK * QBLK;            // 81,920 each
  const size_t ws_needed = (po_elems + 2 * ml_elems) * sizeof(float);

  if (ws_size >= ws_needed) {
    float* PO = (float*)d_ws;
    float* PM = PO + po_elems;
    float* PL = PM + ml_elems;
    attn_partial<<<NTASK, 256, 0, stream>>>(Q, K, V, PO, PM, PL);
    attn_combine<<<(SS / QBLK) * HH, 256, 0, stream>>>(PO, PM, PL, O);
  } else {
    attn_fwd<<<(SS / QBLK) * HH, 256, 0, stream>>>(Q, K, V, O);
  }
}